// Round 3
// baseline (122.751 us; speedup 1.0000x reference)
//
#include <hip/hip_runtime.h>
#include <hip/hip_cooperative_groups.h>

namespace cg = cooperative_groups;

#define BATCH 4
#define SEQ   512
#define DIM   128

typedef _Float16 half8 __attribute__((ext_vector_type(8)));
typedef _Float16 half4 __attribute__((ext_vector_type(4)));
typedef float    f32x4 __attribute__((ext_vector_type(4)));

static __device__ __forceinline__ half8 cvt_h8(const float4 a, const float4 b) {
    half8 h;
    h[0] = (_Float16)a.x; h[1] = (_Float16)a.y; h[2] = (_Float16)a.z; h[3] = (_Float16)a.w;
    h[4] = (_Float16)b.x; h[5] = (_Float16)b.y; h[6] = (_Float16)b.z; h[7] = (_Float16)b.w;
    return h;
}

// ---------------------------------------------------------------------------
// Single cooperative kernel, 256 blocks x 512 threads (8 waves/CU, 2/SIMD).
//
// Phase 1 (proj): block covers 64 token-rows x 16 cols (same partition as the
// verified R1 k_proj, but split across 8 waves instead of 4):
//   waves 0-3: k,v projections for m-tile w      -> ekk (e, e*v) f16
//   waves 4-7: q projection for m-tile w-4       -> qoutT (transposed f32)
//              + this block's 1/256 slice of exp(pos) -> ep_h f16
// grid.sync()
// Phase 2 (AFT): each of the 2048 waves owns one 16m x 16t tile:
//   D[m][t] = sum_j ekk[b][m][j] * ep[t][j]; even m = den, odd m = num.
//   out[b][t][d] = qT[b][d][t] * num/den.
// ---------------------------------------------------------------------------
__global__ __launch_bounds__(512, 2) void k_coop(
    const float* __restrict__ x,
    const float* __restrict__ Wq, const float* __restrict__ bq,
    const float* __restrict__ Wk, const float* __restrict__ bk,
    const float* __restrict__ Wv, const float* __restrict__ bv,
    const float* __restrict__ pos,
    _Float16* __restrict__ ekk, _Float16* __restrict__ ep_h,
    float* __restrict__ qoutT, float* __restrict__ out)
{
    const int tid  = threadIdx.x;
    const int lane = tid & 63;
    const int w    = tid >> 6;      // 0..7
    const int l15  = lane & 15;
    const int quad = lane >> 4;
    const int bid  = blockIdx.x;

    // ---------------- Phase 1: projections ----------------
    const int n0 = (bid & 7) * 16;              // col tile
    const int c  = n0 + l15;

    if (w < 4) {
        // k,v projection for m-tile w
        const int mglob = (bid >> 3) * 64 + w * 16;
        const float* xa  = x  + (mglob + l15) * DIM + quad * 8;
        const float* wkr = Wk + c * DIM + quad * 8;
        const float* wvr = Wv + c * DIM + quad * 8;

        f32x4 ak = {0.f, 0.f, 0.f, 0.f};
        f32x4 av = {0.f, 0.f, 0.f, 0.f};
#pragma unroll
        for (int ks = 0; ks < 4; ++ks) {
            const half8 a  = cvt_h8(*(const float4*)(xa + ks * 32),
                                    *(const float4*)(xa + ks * 32 + 4));
            const half8 b1 = cvt_h8(*(const float4*)(wkr + ks * 32),
                                    *(const float4*)(wkr + ks * 32 + 4));
            const half8 b2 = cvt_h8(*(const float4*)(wvr + ks * 32),
                                    *(const float4*)(wvr + ks * 32 + 4));
            ak = __builtin_amdgcn_mfma_f32_16x16x32_f16(a, b1, ak, 0, 0, 0);
            av = __builtin_amdgcn_mfma_f32_16x16x32_f16(a, b2, av, 0, 0, 0);
        }
        const float bkv = bk[c];
        const float bvv = bv[c];
        const int mrow = mglob + quad * 4;
        const int b    = mrow >> 9;
        const int tok  = mrow & 511;
        half4 eh, evh;
#pragma unroll
        for (int r = 0; r < 4; ++r) {
            const float e  = __expf(ak[r] + bkv);
            const float vv = av[r] + bvv;
            eh[r]  = (_Float16)e;
            evh[r] = (_Float16)(e * vv);
        }
        *(half4*)(ekk + ((b * 256) + 2 * c + 0) * SEQ + tok) = eh;
        *(half4*)(ekk + ((b * 256) + 2 * c + 1) * SEQ + tok) = evh;
    } else {
        // q projection for m-tile w-4
        const int mglob = (bid >> 3) * 64 + (w - 4) * 16;
        const float* xa  = x  + (mglob + l15) * DIM + quad * 8;
        const float* wqr = Wq + c * DIM + quad * 8;

        f32x4 aq = {0.f, 0.f, 0.f, 0.f};
#pragma unroll
        for (int ks = 0; ks < 4; ++ks) {
            const half8 a  = cvt_h8(*(const float4*)(xa + ks * 32),
                                    *(const float4*)(xa + ks * 32 + 4));
            const half8 b0 = cvt_h8(*(const float4*)(wqr + ks * 32),
                                    *(const float4*)(wqr + ks * 32 + 4));
            aq = __builtin_amdgcn_mfma_f32_16x16x32_f16(a, b0, aq, 0, 0, 0);
        }
        const float bqv = bq[c];
        const int mrow = mglob + quad * 4;
        const int b    = mrow >> 9;
        const int tok  = mrow & 511;
        float4 q4;
#pragma unroll
        for (int r = 0; r < 4; ++r)
            ((float*)&q4)[r] = 1.f / (1.f + __expf(-(aq[r] + bqv)));
        *(float4*)(qoutT + ((b * DIM) + c) * SEQ + tok) = q4;

        // exp(pos) conversion: 4 waves x 64 lanes x 4 floats = 1024 / block
        const int i = (bid * 256 + (w - 4) * 64 + lane) * 4;
        const float4 p = *(const float4*)(pos + i);
        half4 h;
        h[0] = (_Float16)__expf(p.x); h[1] = (_Float16)__expf(p.y);
        h[2] = (_Float16)__expf(p.z); h[3] = (_Float16)__expf(p.w);
        *(half4*)(ep_h + i) = h;
    }

    cg::this_grid().sync();

    // ---------------- Phase 2: AFT, one 16x16 tile per wave ----------------
    const int widx = bid * 8 + w;          // 0..2047
    const int b2   = widx >> 9;            // batch
    const int r2   = widx & 511;
    const int m0   = (r2 >> 5) * 16;       // [0,256)
    const int t0   = (r2 & 31) * 16;       // [0,512)

    const _Float16* arow = ekk  + ((b2 * 256) + m0 + l15) * SEQ + quad * 8;
    const _Float16* brow = ep_h + (t0 + l15) * SEQ + quad * 8;

    f32x4 acc = {0.f, 0.f, 0.f, 0.f};
#pragma unroll
    for (int ks = 0; ks < 16; ++ks) {      // K = 512, 32 per step
        const half8 af = *(const half8*)(arow + ks * 32);
        const half8 bf = *(const half8*)(brow + ks * 32);
        acc = __builtin_amdgcn_mfma_f32_16x16x32_f16(af, bf, acc, 0, 0, 0);
    }

    // lane rows m0+quad*4+{0..3} = den(d0),num(d0),den(d0+1),num(d0+1); col t0+l15
    const int d0 = (m0 + quad * 4) >> 1;
    const int t  = t0 + l15;
    const float q0 = qoutT[((b2 * DIM) + d0) * SEQ + t];
    const float q1 = qoutT[((b2 * DIM) + d0 + 1) * SEQ + t];
    float2 o;
    o.x = q0 * acc[1] / acc[0];
    o.y = q1 * acc[3] / acc[2];
    *(float2*)(out + ((b2 * SEQ) + t) * DIM + d0) = o;
}

// ---------------------------------------------------------------------------
extern "C" void kernel_launch(void* const* d_in, const int* in_sizes, int n_in,
                              void* d_out, int out_size, void* d_ws, size_t ws_size,
                              hipStream_t stream) {
    const float* x   = (const float*)d_in[0];
    const float* Wq  = (const float*)d_in[1];
    const float* bq  = (const float*)d_in[2];
    const float* Wk  = (const float*)d_in[3];
    const float* bk  = (const float*)d_in[4];
    const float* bv_ = (const float*)d_in[6];
    const float* Wv  = (const float*)d_in[5];
    const float* pos = (const float*)d_in[7];
    const float* bk_ = bk;

    float* outp = (float*)d_out;
    char*  ws   = (char*)d_ws;

    _Float16* ep_h  = (_Float16*)(ws);                      // 512 KB
    _Float16* ekk   = (_Float16*)(ws + (512 << 10));        // 1 MB
    float*    qoutT = (float*)   (ws + (1536 << 10));       // 1 MB

    void* args[] = {
        (void*)&x, (void*)&Wq, (void*)&bq, (void*)&bk_, (void*)&bk,
        (void*)&Wv, (void*)&bv_, (void*)&pos,
        (void*)&ekk, (void*)&ep_h, (void*)&qoutT, (void*)&outp
    };
    // NOTE: args must match k_coop's parameter order exactly:
    // (x, Wq, bq, Wk, bk, Wv, bv, pos, ekk, ep_h, qoutT, out)
    const float* Wk_ = Wk;
    void* args_fixed[] = {
        (void*)&x, (void*)&Wq, (void*)&bq, (void*)&Wk_, (void*)&bk,
        (void*)&Wv, (void*)&bv_, (void*)&pos,
        (void*)&ekk, (void*)&ep_h, (void*)&qoutT, (void*)&outp
    };
    (void)args;
    hipLaunchCooperativeKernel((const void*)k_coop, dim3(256), dim3(512),
                               args_fixed, 0, stream);
}

// Round 4
// 90.869 us; speedup vs baseline: 1.3509x; 1.3509x over previous
//
#include <hip/hip_runtime.h>

#define BATCH 4
#define SEQ   512
#define DIM   128

typedef _Float16 half8 __attribute__((ext_vector_type(8)));
typedef _Float16 half4 __attribute__((ext_vector_type(4)));
typedef float    f32x4 __attribute__((ext_vector_type(4)));

static __device__ __forceinline__ half8 cvt_h8(const float4 a, const float4 b) {
    half8 h;
    h[0] = (_Float16)a.x; h[1] = (_Float16)a.y; h[2] = (_Float16)a.z; h[3] = (_Float16)a.w;
    h[4] = (_Float16)b.x; h[5] = (_Float16)b.y; h[6] = (_Float16)b.z; h[7] = (_Float16)b.w;
    return h;
}

// ekk LDS tile: m in [0,32) (= 2*d_local + {0:e, 1:e*v}), jl in [0,128) chunk-j.
// XOR swizzle (byte ^= (m&7)<<4): kills the 16-row stride-256B bank conflict on
// ds_read_b128; preserves half4 (8B) and half8 (16B) contiguity (bits 0..2 of
// the half index untouched).
#define EIDX(m, jl) ((m) * 128 + ((jl) ^ (((m) & 7) << 3)))

// ---------------------------------------------------------------------------
// Single fused kernel, no grid sync, bounded recompute.
// Grid = 256 blocks = 4 b x 8 d-groups(16 cols) x 8 t-slices(64 t). 512 thr.
// Per block, loop over 4 j-chunks of 128 tokens:
//   phase A (per wave w): k,v proj for j-tile w (16 tokens x 16 cols),
//     epilogue exp -> ekk_lds[2c(+1)][jl] (transposed, swizzled);
//     concurrently build AFT B-fragments in-reg: exp(pos[t][j]) from f32 loads.
//   barrier; phase B: acc += mfma(ekk_lds rows, bfrag); barrier.
// After loop: waves 0-3 compute q (MFMA) -> q_lds; barrier;
// epilogue: out[b][t][d] = q * num/den.
// Proj work duplicated 8x across t-slices (1 GFLOP total - cheap); exp(pos)
// recomputed per consumer wave (transcendental unit, negligible).
// ---------------------------------------------------------------------------
__global__ __launch_bounds__(512) void k_fused(
    const float* __restrict__ x,
    const float* __restrict__ Wq, const float* __restrict__ bq,
    const float* __restrict__ Wk, const float* __restrict__ bk,
    const float* __restrict__ Wv, const float* __restrict__ bv,
    const float* __restrict__ pos,
    float* __restrict__ out)
{
    __shared__ _Float16 ekk_lds[32 * 128];   // 8 KB
    __shared__ float    q_lds[64 * 17];      // 4.25 KB, padded stride 17

    const int tid  = threadIdx.x;
    const int lane = tid & 63;
    const int w    = tid >> 6;      // 0..7
    const int l15  = lane & 15;
    const int quad = lane >> 4;

    const int bid = blockIdx.x;
    const int b   = bid >> 6;            // batch
    const int dg  = (bid >> 3) & 7;      // d-group
    const int ts  = bid & 7;             // t-slice
    const int d0g = dg * 16;
    const int t0g = ts * 64;

    // hoisted W fragments for k,v (B-operand rows = cols d0g + l15)
    const float* wkr = Wk + (d0g + l15) * DIM + quad * 8;
    const float* wvr = Wv + (d0g + l15) * DIM + quad * 8;
    half8 wkf[4], wvf[4];
#pragma unroll
    for (int ks = 0; ks < 4; ++ks) {
        wkf[ks] = cvt_h8(*(const float4*)(wkr + ks * 32), *(const float4*)(wkr + ks * 32 + 4));
        wvf[ks] = cvt_h8(*(const float4*)(wvr + ks * 32), *(const float4*)(wvr + ks * 32 + 4));
    }
    const float bkv = bk[d0g + l15];
    const float bvv = bv[d0g + l15];

    const float* xb = x + b * SEQ * DIM;

    // AFT wave tile: wm = m-half (16 rows), wt = t-tile (16 cols)
    const int wm   = w & 1;
    const int wt   = w >> 1;             // 0..3
    const int m0   = wm * 16;
    const int trow = t0g + wt * 16 + l15;    // global t for B-fragment row

    f32x4 acc = {0.f, 0.f, 0.f, 0.f};

    for (int ch = 0; ch < 4; ++ch) {
        const int j0 = ch * 128;

        // ---- phase A1: k,v proj chains for j-tile w ----
        const float* xa = xb + (j0 + w * 16 + l15) * DIM + quad * 8;
        f32x4 ak = {0.f, 0.f, 0.f, 0.f};
        f32x4 av = {0.f, 0.f, 0.f, 0.f};
#pragma unroll
        for (int ks = 0; ks < 4; ++ks) {
            const half8 a = cvt_h8(*(const float4*)(xa + ks * 32),
                                   *(const float4*)(xa + ks * 32 + 4));
            ak = __builtin_amdgcn_mfma_f32_16x16x32_f16(a, wkf[ks], ak, 0, 0, 0);
            av = __builtin_amdgcn_mfma_f32_16x16x32_f16(a, wvf[ks], av, 0, 0, 0);
        }

        // ---- phase A2: AFT B-fragments in-reg (pos -> exp -> f16) ----
        half8 bfrag[4];
#pragma unroll
        for (int ks = 0; ks < 4; ++ks) {
            const float* pp = pos + trow * SEQ + j0 + ks * 32 + quad * 8;
            const float4 p0 = *(const float4*)pp;
            const float4 p1 = *(const float4*)(pp + 4);
            half8 h;
            h[0] = (_Float16)__expf(p0.x); h[1] = (_Float16)__expf(p0.y);
            h[2] = (_Float16)__expf(p0.z); h[3] = (_Float16)__expf(p0.w);
            h[4] = (_Float16)__expf(p1.x); h[5] = (_Float16)__expf(p1.y);
            h[6] = (_Float16)__expf(p1.z); h[7] = (_Float16)__expf(p1.w);
            bfrag[ks] = h;
        }

        // ---- phase A3: proj epilogue -> swizzled LDS (transposed) ----
        // lane holds D rows tok_local = w*16 + quad*4 + r, col c = l15
        const int jl0 = w * 16 + quad * 4;
        half4 eh, evh;
#pragma unroll
        for (int r = 0; r < 4; ++r) {
            const float e  = __expf(ak[r] + bkv);
            const float vv = av[r] + bvv;
            eh[r]  = (_Float16)e;
            evh[r] = (_Float16)(e * vv);
        }
        *(half4*)&ekk_lds[EIDX(2 * l15,     jl0)] = eh;
        *(half4*)&ekk_lds[EIDX(2 * l15 + 1, jl0)] = evh;

        __syncthreads();

        // ---- phase B: AFT accumulate (K = 128 per chunk) ----
#pragma unroll
        for (int ks = 0; ks < 4; ++ks) {
            const half8 af = *(const half8*)&ekk_lds[EIDX(m0 + l15, ks * 32 + quad * 8)];
            acc = __builtin_amdgcn_mfma_f32_16x16x32_f16(af, bfrag[ks], acc, 0, 0, 0);
        }

        __syncthreads();   // before next chunk overwrites ekk_lds
    }

    // ---- q phase: waves 0-3, one 16-token x 16-col tile each ----
    if (w < 4) {
        const float* wqr = Wq + (d0g + l15) * DIM + quad * 8;
        half8 wqf[4];
#pragma unroll
        for (int ks = 0; ks < 4; ++ks)
            wqf[ks] = cvt_h8(*(const float4*)(wqr + ks * 32), *(const float4*)(wqr + ks * 32 + 4));
        const float* xq = xb + (t0g + w * 16 + l15) * DIM + quad * 8;
        f32x4 aq = {0.f, 0.f, 0.f, 0.f};
#pragma unroll
        for (int ks = 0; ks < 4; ++ks) {
            const half8 a = cvt_h8(*(const float4*)(xq + ks * 32),
                                   *(const float4*)(xq + ks * 32 + 4));
            aq = __builtin_amdgcn_mfma_f32_16x16x32_f16(a, wqf[ks], aq, 0, 0, 0);
        }
        const float bqv = bq[d0g + l15];
#pragma unroll
        for (int r = 0; r < 4; ++r)
            q_lds[(w * 16 + quad * 4 + r) * 17 + l15] =
                1.f / (1.f + __expf(-(aq[r] + bqv)));
    }
    __syncthreads();

    // ---- epilogue ----
    // wave (wm,wt): lane rows m = m0+quad*4+{0..3} = den(d),num(d),den(d+1),num(d+1)
    // col t = wt*16 + l15 (local within 64-t slice)
    const int dl0 = wm * 8 + quad * 2;         // local d (even)
    const int tl  = wt * 16 + l15;             // local t
    const float q0 = q_lds[tl * 17 + dl0];
    const float q1 = q_lds[tl * 17 + dl0 + 1];
    float2 o;
    o.x = q0 * acc[1] / acc[0];
    o.y = q1 * acc[3] / acc[2];
    *(float2*)(out + (b * SEQ + t0g + tl) * DIM + d0g + dl0) = o;
}

// ---------------------------------------------------------------------------
extern "C" void kernel_launch(void* const* d_in, const int* in_sizes, int n_in,
                              void* d_out, int out_size, void* d_ws, size_t ws_size,
                              hipStream_t stream) {
    const float* x   = (const float*)d_in[0];
    const float* Wq  = (const float*)d_in[1];
    const float* bq  = (const float*)d_in[2];
    const float* Wk  = (const float*)d_in[3];
    const float* bk  = (const float*)d_in[4];
    const float* Wv  = (const float*)d_in[5];
    const float* bv  = (const float*)d_in[6];
    const float* pos = (const float*)d_in[7];

    (void)d_ws; (void)ws_size;   // zero workspace

    k_fused<<<256, 512, 0, stream>>>(x, Wq, bq, Wk, bk, Wv, bv, pos, (float*)d_out);
}

// Round 5
// 80.612 us; speedup vs baseline: 1.5227x; 1.1272x over previous
//
#include <hip/hip_runtime.h>

#define BATCH 4
#define SEQ   512
#define DIM   128

typedef _Float16 half8 __attribute__((ext_vector_type(8)));
typedef _Float16 half4 __attribute__((ext_vector_type(4)));
typedef float    f32x4 __attribute__((ext_vector_type(4)));

// ---------------------------------------------------------------------------
// K0 prep: f32 -> f16 conversions.
//   blocks [0,128)   : x      (262144)          -> x_h
//   blocks [128,256) : pos    (262144), exp()   -> ep_h
//   blocks [256,280) : Wq/Wk/Wv (16384 each)    -> wq_h/wk_h/wv_h
// ---------------------------------------------------------------------------
__global__ __launch_bounds__(256) void k_prep(
    const float* __restrict__ x, const float* __restrict__ pos,
    const float* __restrict__ Wq, const float* __restrict__ Wk,
    const float* __restrict__ Wv,
    _Float16* __restrict__ x_h, _Float16* __restrict__ ep_h,
    _Float16* __restrict__ wq_h, _Float16* __restrict__ wk_h,
    _Float16* __restrict__ wv_h)
{
    const int blk = blockIdx.x;
    const int tid = threadIdx.x;
    if (blk < 128) {
        const int i = (blk * 256 + tid) * 8;
        const float4 p0 = *(const float4*)(x + i);
        const float4 p1 = *(const float4*)(x + i + 4);
        half8 h;
        h[0]=(_Float16)p0.x; h[1]=(_Float16)p0.y; h[2]=(_Float16)p0.z; h[3]=(_Float16)p0.w;
        h[4]=(_Float16)p1.x; h[5]=(_Float16)p1.y; h[6]=(_Float16)p1.z; h[7]=(_Float16)p1.w;
        *(half8*)(x_h + i) = h;
    } else if (blk < 256) {
        const int i = ((blk - 128) * 256 + tid) * 8;
        const float4 p0 = *(const float4*)(pos + i);
        const float4 p1 = *(const float4*)(pos + i + 4);
        half8 h;
        h[0]=(_Float16)__expf(p0.x); h[1]=(_Float16)__expf(p0.y);
        h[2]=(_Float16)__expf(p0.z); h[3]=(_Float16)__expf(p0.w);
        h[4]=(_Float16)__expf(p1.x); h[5]=(_Float16)__expf(p1.y);
        h[6]=(_Float16)__expf(p1.z); h[7]=(_Float16)__expf(p1.w);
        *(half8*)(ep_h + i) = h;
    } else {
        const int r = blk - 256;                  // 0..23
        const float* src = (r < 8) ? Wq : ((r < 16) ? Wk : Wv);
        _Float16* dst    = (r < 8) ? wq_h : ((r < 16) ? wk_h : wv_h);
        const int i = ((r & 7) * 256 + tid) * 8;
        const float4 p0 = *(const float4*)(src + i);
        const float4 p1 = *(const float4*)(src + i + 4);
        half8 h;
        h[0]=(_Float16)p0.x; h[1]=(_Float16)p0.y; h[2]=(_Float16)p0.z; h[3]=(_Float16)p0.w;
        h[4]=(_Float16)p1.x; h[5]=(_Float16)p1.y; h[6]=(_Float16)p1.z; h[7]=(_Float16)p1.w;
        *(half8*)(dst + i) = h;
    }
}

// ---------------------------------------------------------------------------
// K1 proj (MFMA): D[token][col] = x @ W^T for q,k,v simultaneously.
// Wave tile 16m(token) x 16n(col); block = 4 waves stacked in m.
// Grid = 32 x 8 = 256 blocks.
// Epilogue:
//   q[b][tok][col]            = sigmoid(dq + bq)   (f32, natural layout)
//   ekk[b][2c+0][tok] (f16)   = exp(dk + bk)              (den operand)
//   ekk[b][2c+1][tok] (f16)   = exp(dk + bk)*(dv + bv)    (num operand)
// ---------------------------------------------------------------------------
__global__ __launch_bounds__(256) void k_proj(
    const _Float16* __restrict__ x_h,
    const _Float16* __restrict__ wq_h, const float* __restrict__ bq,
    const _Float16* __restrict__ wk_h, const float* __restrict__ bk,
    const _Float16* __restrict__ wv_h, const float* __restrict__ bv,
    float* __restrict__ qout, _Float16* __restrict__ ekk)
{
    const int tid  = threadIdx.x;
    const int lane = tid & 63;
    const int wave = tid >> 6;
    const int l15  = lane & 15;
    const int quad = lane >> 4;

    const int n0 = (blockIdx.x & 7) * 16;               // col tile
    const int m0 = (blockIdx.x >> 3) * 64 + wave * 16;  // token-row tile

    const _Float16* xa = x_h  + (m0 + l15) * DIM + quad * 8;
    const _Float16* wq = wq_h + (n0 + l15) * DIM + quad * 8;
    const _Float16* wk = wk_h + (n0 + l15) * DIM + quad * 8;
    const _Float16* wv = wv_h + (n0 + l15) * DIM + quad * 8;

    f32x4 aq = {0.f, 0.f, 0.f, 0.f};
    f32x4 ak = {0.f, 0.f, 0.f, 0.f};
    f32x4 av = {0.f, 0.f, 0.f, 0.f};

#pragma unroll
    for (int ks = 0; ks < 4; ++ks) {            // K = 128, 32 per step
        const half8 a  = *(const half8*)(xa + ks * 32);
        const half8 b0 = *(const half8*)(wq + ks * 32);
        const half8 b1 = *(const half8*)(wk + ks * 32);
        const half8 b2 = *(const half8*)(wv + ks * 32);
        aq = __builtin_amdgcn_mfma_f32_16x16x32_f16(a, b0, aq, 0, 0, 0);
        ak = __builtin_amdgcn_mfma_f32_16x16x32_f16(a, b1, ak, 0, 0, 0);
        av = __builtin_amdgcn_mfma_f32_16x16x32_f16(a, b2, av, 0, 0, 0);
    }

    const int c   = n0 + l15;
    const float bqv = bq[c];
    const float bkv = bk[c];
    const float bvv = bv[c];

    const int mrow = m0 + quad * 4;   // first of 4 token rows this lane holds
    const int b    = mrow >> 9;       // /512 (all 4 rows same batch)
    const int tok  = mrow & 511;

    half4 eh, evh;
#pragma unroll
    for (int r = 0; r < 4; ++r) {
        const float e  = __expf(ak[r] + bkv);
        const float vv = av[r] + bvv;
        const float qv = 1.f / (1.f + __expf(-(aq[r] + bqv)));
        eh[r]  = (_Float16)e;
        evh[r] = (_Float16)(e * vv);
        qout[(b * SEQ + tok + r) * DIM + c] = qv;
    }
    *(half4*)(ekk + ((b * 256) + 2 * c + 0) * SEQ + tok) = eh;
    *(half4*)(ekk + ((b * 256) + 2 * c + 1) * SEQ + tok) = evh;
}

// ---------------------------------------------------------------------------
// K2 AFT (MFMA, zero LDS): per b, D[m][t] = sum_j ekk[m][j] * ep[t][j]
//   m in [0,256): even rows = den (ek), odd rows = num (ekv).
// Wave tile 16m x 32t (2 MFMAs/k-step); block = 4 waves (2m x 2t) = 32m x 64t.
// Grid = 256 blocks; operands are direct 16B global loads (L2-resident).
// Epilogue: out[b][t][d] = q[b][t][d] * num/den.
// ---------------------------------------------------------------------------
__global__ __launch_bounds__(256) void k_aft(
    const _Float16* __restrict__ ekk,
    const _Float16* __restrict__ ep_h,
    const float* __restrict__ qout,
    float* __restrict__ out)
{
    const int tid  = threadIdx.x;
    const int lane = tid & 63;
    const int wave = tid >> 6;
    const int l15  = lane & 15;
    const int quad = lane >> 4;
    const int wm   = wave & 1;
    const int wn   = wave >> 1;

    const int b  = blockIdx.x >> 6;
    const int m0 = (((blockIdx.x >> 3) & 7) * 32) + wm * 16;  // [0,256)
    const int t0 = ((blockIdx.x & 7) * 64) + wn * 32;         // [0,512)

    const _Float16* arow  = ekk  + ((b * 256) + m0 + l15) * SEQ + quad * 8;
    const _Float16* brow0 = ep_h + (t0 + l15) * SEQ + quad * 8;
    const _Float16* brow1 = brow0 + 16 * SEQ;

    f32x4 acc0 = {0.f, 0.f, 0.f, 0.f};
    f32x4 acc1 = {0.f, 0.f, 0.f, 0.f};

#pragma unroll
    for (int ks = 0; ks < 16; ++ks) {           // K = 512, 32 per step
        const half8 a  = *(const half8*)(arow  + ks * 32);
        const half8 b0 = *(const half8*)(brow0 + ks * 32);
        const half8 b1 = *(const half8*)(brow1 + ks * 32);
        acc0 = __builtin_amdgcn_mfma_f32_16x16x32_f16(a, b0, acc0, 0, 0, 0);
        acc1 = __builtin_amdgcn_mfma_f32_16x16x32_f16(a, b1, acc1, 0, 0, 0);
    }

    // lane holds rows m0+quad*4+{0..3} = (den,num) for d0 and d0+1
    const int d0 = (m0 + quad * 4) >> 1;   // even
#pragma unroll
    for (int i = 0; i < 2; ++i) {
        const f32x4 acc = i ? acc1 : acc0;
        const int t = t0 + i * 16 + l15;
        const float2 qv = *(const float2*)(qout + ((b * SEQ) + t) * DIM + d0);
        float2 o;
        o.x = qv.x * acc[1] / acc[0];
        o.y = qv.y * acc[3] / acc[2];
        *(float2*)(out + ((b * SEQ) + t) * DIM + d0) = o;
    }
}

// ---------------------------------------------------------------------------
extern "C" void kernel_launch(void* const* d_in, const int* in_sizes, int n_in,
                              void* d_out, int out_size, void* d_ws, size_t ws_size,
                              hipStream_t stream) {
    const float* x   = (const float*)d_in[0];
    const float* Wq  = (const float*)d_in[1];
    const float* bq  = (const float*)d_in[2];
    const float* Wk  = (const float*)d_in[3];
    const float* bk  = (const float*)d_in[4];
    const float* Wv  = (const float*)d_in[5];
    const float* bv  = (const float*)d_in[6];
    const float* pos = (const float*)d_in[7];

    float* outp = (float*)d_out;
    char*  ws   = (char*)d_ws;

    _Float16* x_h  = (_Float16*)(ws);                       // 512 KB
    _Float16* ep_h = (_Float16*)(ws + (512 << 10));         // 512 KB
    _Float16* ekk  = (_Float16*)(ws + (1024 << 10));        // 1 MB
    _Float16* wq_h = (_Float16*)(ws + (2048 << 10));        // 32 KB
    _Float16* wk_h = (_Float16*)(ws + (2080 << 10));        // 32 KB
    _Float16* wv_h = (_Float16*)(ws + (2112 << 10));        // 32 KB
    float*    qout = (float*)   (ws + (2144 << 10));        // 1 MB

    k_prep<<<280, 256, 0, stream>>>(x, pos, Wq, Wk, Wv, x_h, ep_h, wq_h, wk_h, wv_h);
    k_proj<<<256, 256, 0, stream>>>(x_h, wq_h, bq, wk_h, bk, wv_h, bv, qout, ekk);
    k_aft<<<256, 256, 0, stream>>>(ekk, ep_h, qout, outp);
}